// Round 6
// baseline (320.040 us; speedup 1.0000x reference)
//
#include <hip/hip_runtime.h>
#include <hip/hip_bf16.h>

#define B_DIM 8192
#define IN_DIM 2048
#define OUT_DIM 2048
#define K2 (2 * IN_DIM)  // hi|lo concatenated K = 4096

typedef __attribute__((ext_vector_type(8))) __bf16 bf16x8;
typedef __attribute__((ext_vector_type(4))) float f32x4;

__device__ __forceinline__ unsigned short f32_to_bf16_rne(float f) {
    unsigned u = __float_as_uint(f);
    unsigned r = (u + 0x7FFFu + ((u >> 16) & 1u)) >> 16;
    return (unsigned short)r;
}
__device__ __forceinline__ float bf16u_to_f32(unsigned short h) {
    return __uint_as_float(((unsigned)h) << 16);
}

__device__ __forceinline__ void gload16(const void* g, void* l) {
    __builtin_amdgcn_global_load_lds(
        (const __attribute__((address_space(1))) void*)g,
        (__attribute__((address_space(3))) void*)l,
        16, 0, 0);
}

// ---------------- Stage 1: per-column partial sums (deterministic) -------------
__global__ void k_stats(const float* __restrict__ x, float* __restrict__ psum,
                        float* __restrict__ psq) {
    int col = blockIdx.x * 256 + threadIdx.x;
    int chunk = blockIdx.y;
    const float* p = x + (size_t)chunk * 256 * IN_DIM + col;
    float s = 0.f, s2 = 0.f;
#pragma unroll 8
    for (int r = 0; r < 256; ++r) {
        float v = p[(size_t)r * IN_DIM];
        s += v;
        s2 = fmaf(v, v, s2);
    }
    psum[chunk * IN_DIM + col] = s;
    psq[chunk * IN_DIM + col] = s2;
}

// ---------------- Stage 2: finalize mean/var -> scale/shift --------------------
__global__ void k_finalize(const float* __restrict__ psum, const float* __restrict__ psq,
                           const float* __restrict__ gamma, const float* __restrict__ beta,
                           float* __restrict__ scale, float* __restrict__ shift) {
    int c = blockIdx.x * 256 + threadIdx.x;
    float s = 0.f, s2 = 0.f;
#pragma unroll
    for (int ch = 0; ch < 32; ++ch) {
        s += psum[ch * IN_DIM + c];
        s2 += psq[ch * IN_DIM + c];
    }
    float mean = s * (1.0f / B_DIM);
    float var = fmaf(-mean, mean, s2 * (1.0f / B_DIM));
    float sc = gamma[c] * rsqrtf(var + 1e-5f);
    scale[c] = sc;
    shift[c] = fmaf(-mean, sc, beta[c]);
}

// ---------------- Stage 3: xn -> bf16 hi|lo concatenated A [8192][4096] --------
__global__ void k_prep_a(const float* __restrict__ x, const float* __restrict__ scale,
                         const float* __restrict__ shift, unsigned short* __restrict__ Acat) {
    int row = blockIdx.x;
    int c0 = threadIdx.x * 8;
    const float4* px = (const float4*)(x + (size_t)row * IN_DIM + c0);
    float4 v0 = px[0], v1 = px[1];
    const float4* ps = (const float4*)(scale + c0);
    float4 s0 = ps[0], s1 = ps[1];
    const float4* pb = (const float4*)(shift + c0);
    float4 b0 = pb[0], b1 = pb[1];
    float xs[8] = {v0.x, v0.y, v0.z, v0.w, v1.x, v1.y, v1.z, v1.w};
    float ss[8] = {s0.x, s0.y, s0.z, s0.w, s1.x, s1.y, s1.z, s1.w};
    float bb[8] = {b0.x, b0.y, b0.z, b0.w, b1.x, b1.y, b1.z, b1.w};
    union { unsigned short u[8]; uint4 v; } hi, lo;
#pragma unroll
    for (int j = 0; j < 8; ++j) {
        float xn = fmaf(xs[j], ss[j], bb[j]);
        unsigned short h = f32_to_bf16_rne(xn);
        float r = xn - bf16u_to_f32(h);
        hi.u[j] = h;
        lo.u[j] = f32_to_bf16_rne(r);
    }
    size_t base = (size_t)row * K2;
    *(uint4*)(Acat + base + c0) = hi.v;
    *(uint4*)(Acat + base + IN_DIM + c0) = lo.v;
}

// ---------------- Stage 4: weight sign -> bf16 +-1 [2048][2048] ----------------
__global__ void k_prep_b(const float* __restrict__ w, unsigned short* __restrict__ Bsgn) {
    int row = blockIdx.x;
    int c0 = threadIdx.x * 8;
    const float4* pw = (const float4*)(w + (size_t)row * IN_DIM + c0);
    float4 v0 = pw[0], v1 = pw[1];
    float wv[8] = {v0.x, v0.y, v0.z, v0.w, v1.x, v1.y, v1.z, v1.w};
    union { unsigned short u[8]; uint4 v; } sb;
#pragma unroll
    for (int j = 0; j < 8; ++j) sb.u[j] = (wv[j] >= 0.0f) ? 0x3F80u : 0xBF80u;
    *(uint4*)(Bsgn + (size_t)row * IN_DIM + c0) = sb.v;
}

// ---------------- Stage 5: 256x256 tile, A direct-to-reg, B 4-deep LDS ring ----
// A fragments load global->VGPR (double-buffered af0/af1, issued 1 tile ahead).
// B stays LDS (4x reuse), 4-buffer ring, staged 2 tiles ahead. One barrier +
// one vmcnt(0) per K-tile; every load has >=3 phases (~1800 cy) of slack.
#define BM 256
#define BN 256
#define BK 64
#define MT (B_DIM / BM)    // 32
#define NT (OUT_DIM / BN)  // 8
#define NWG (MT * NT)      // 256
#define NKT (K2 / BK)      // 64
#define TILE_E (BN * BK)   // 16384 elems = 32 KB (one B buffer)

#define MEMF() asm volatile("" ::: "memory")
#define BARRIER() do { MEMF(); __builtin_amdgcn_s_barrier(); MEMF(); } while (0)
#define WAITVM(N) asm volatile("s_waitcnt vmcnt(" #N ")" ::: "memory")

__global__ __launch_bounds__(512, 2) void k_gemm(const unsigned short* __restrict__ A,
                                                 const unsigned short* __restrict__ Bsgn,
                                                 float* __restrict__ out) {
    __shared__ __align__(16) unsigned short sh[4 * TILE_E];  // 128 KiB B ring

    // T1: XCD-aware swizzle (256 % 8 == 0 -> bijective)
    int bid = blockIdx.x;
    int swz = (bid & 7) * (NWG / 8) + (bid >> 3);
    int mt = swz >> 3, nt = swz & 7;
    int m0 = mt * BM, n0 = nt * BN;

    int t = threadIdx.x;
    int lane = t & 63, w = t >> 6;
    int wm = w >> 1, wn = w & 1;         // 4m x 2n waves; per-wave out 64 x 128
    int lrow = lane & 15, lg = lane >> 4;
    int lq = lane >> 3, lslot = lane & 7;
    int tsl = lslot ^ lq;                // pre-swizzled source slot (row&7 == lq)

    int sl0 = (lg ^ (lane & 7)) << 3;          // ks=0 read slot offset (elems)
    int sl1 = ((lg + 4) ^ (lane & 7)) << 3;    // ks=1

    int bRd = (wn * 128 + lrow) * BK;

    // Per-lane A base: row = m0 + wm*64 + lrow, frag (m,ks) at +m*16 rows, +ks*32+lg*8 cols
    const unsigned short* aBase = A + (size_t)(m0 + wm * 64 + lrow) * K2 + lg * 8;

    // B-chunk(2wn+i): pieces q = wm*2 + j (j=0..1); one gload16/thread per call
    auto stageB = [&](unsigned short* bbuf, int i, int j, int kt) {
        int cb = 2 * wn + i;
        int q = wm * 2 + j;
        const unsigned short* src =
            Bsgn + (size_t)(n0 + cb * 64 + q * 8 + lq) * IN_DIM +
            ((kt * BK) & (IN_DIM - 1)) + tsl * 8;
        gload16(src, bbuf + cb * (64 * BK) + q * 512 + lane * 8);
    };

    f32x4 acc[4][8] = {};

#define LDB(buf, n, sl) (*(const bf16x8*)&(buf)[bRd + (n) * (16 * BK) + (sl)])
#define LOADA(AF, KT)                                                              \
    do {                                                                           \
        const unsigned short* ab_ = aBase + (size_t)(KT) * BK;                     \
        _Pragma("unroll") for (int m_ = 0; m_ < 4; ++m_)                           \
            _Pragma("unroll") for (int ks_ = 0; ks_ < 2; ++ks_)                    \
                AF[m_][ks_] = *(const bf16x8*)(ab_ + (size_t)m_ * 16 * K2 + ks_ * 32); \
    } while (0)
#define MFMA_PAIR(AF, NP, BP)                                                      \
    do {                                                                           \
        __builtin_amdgcn_s_setprio(1);                                             \
        _Pragma("unroll") for (int ks = 0; ks < 2; ++ks)                           \
            _Pragma("unroll") for (int m = 0; m < 4; ++m)                          \
                _Pragma("unroll") for (int i = 0; i < 2; ++i)                      \
                    acc[m][(NP) + i] = __builtin_amdgcn_mfma_f32_16x16x32_bf16(    \
                        AF[m][ks], BP[i][ks], acc[m][(NP) + i], 0, 0, 0);          \
        __builtin_amdgcn_s_setprio(0);                                             \
    } while (0)

    bf16x8 af0[4][2], af1[4][2];
    bf16x8 bpA[2][2], bpB[2][2], bpC[2][2], bpD[2][2];

    // Prologue: stage B(0)->buf0, B(1)->buf1; load af0 = A(0); drain; read bpA(0)
    {
        unsigned short* b0 = (unsigned short*)sh;
        unsigned short* b1 = (unsigned short*)sh + TILE_E;
        stageB(b0, 0, 0, 0); stageB(b0, 0, 1, 0); stageB(b0, 1, 0, 0); stageB(b0, 1, 1, 0);
        stageB(b1, 0, 0, 1); stageB(b1, 0, 1, 1); stageB(b1, 1, 0, 1); stageB(b1, 1, 1, 1);
        LOADA(af0, 0);
        WAITVM(0);
        BARRIER();
#pragma unroll
        for (int i = 0; i < 2; ++i) { bpA[i][0] = LDB((const unsigned short*)sh, i, sl0);
                                      bpA[i][1] = LDB((const unsigned short*)sh, i, sl1); }
    }

    auto tile_body = [&](int T_, bf16x8 (&AFC)[4][2], bf16x8 (&AFN)[4][2]) {
        const unsigned short* bufc = sh + (T_ & 3) * TILE_E;
        const unsigned short* bufn = sh + ((T_ + 1) & 3) * TILE_E;
        unsigned short* bufs = (unsigned short*)sh + ((T_ + 2) & 3) * TILE_E;
        bool st = T_ < NKT - 2, pf = T_ < NKT - 1;

        // ph0: issue all of next-next B staging + next A loads; MFMA n{0,1}
        if (st) { stageB(bufs, 0, 0, T_ + 2); stageB(bufs, 0, 1, T_ + 2);
                  stageB(bufs, 1, 0, T_ + 2); stageB(bufs, 1, 1, T_ + 2); }
        if (pf) { LOADA(AFN, T_ + 1); }
#pragma unroll
        for (int i = 0; i < 2; ++i) { bpB[i][0] = LDB(bufc, 2 + i, sl0); bpB[i][1] = LDB(bufc, 2 + i, sl1); }
        MFMA_PAIR(AFC, 0, bpA);

        // ph1: MFMA n{2,3}
#pragma unroll
        for (int i = 0; i < 2; ++i) { bpC[i][0] = LDB(bufc, 4 + i, sl0); bpC[i][1] = LDB(bufc, 4 + i, sl1); }
        MFMA_PAIR(AFC, 2, bpB);

        // ph2: MFMA n{4,5}
#pragma unroll
        for (int i = 0; i < 2; ++i) { bpD[i][0] = LDB(bufc, 6 + i, sl0); bpD[i][1] = LDB(bufc, 6 + i, sl1); }
        MFMA_PAIR(AFC, 4, bpC);

        // ph3: drain (all loads 3 phases old), barrier; read next bpA; MFMA n{6,7}
        WAITVM(0);
        BARRIER();
        if (pf) {
#pragma unroll
            for (int i = 0; i < 2; ++i) { bpA[i][0] = LDB(bufn, i, sl0); bpA[i][1] = LDB(bufn, i, sl1); }
        }
        MFMA_PAIR(AFC, 6, bpD);
    };

    for (int T = 0; T < NKT; T += 2) {
        tile_body(T, af0, af1);
        tile_body(T + 1, af1, af0);
    }

    // Epilogue: C/D map col=lane&15, row=(lane>>4)*4+reg; fused hardtanh
#pragma unroll
    for (int m = 0; m < 4; ++m) {
#pragma unroll
        for (int n = 0; n < 8; ++n) {
#pragma unroll
            for (int r = 0; r < 4; ++r) {
                int row = m0 + wm * 64 + m * 16 + lg * 4 + r;
                int col = n0 + wn * 128 + n * 16 + lrow;
                float v = acc[m][n][r];
                v = fminf(fmaxf(v, -1.0f), 1.0f);
                out[(size_t)row * OUT_DIM + col] = v;
            }
        }
    }
}

extern "C" void kernel_launch(void* const* d_in, const int* in_sizes, int n_in,
                              void* d_out, int out_size, void* d_ws, size_t ws_size,
                              hipStream_t stream) {
    const float* x = (const float*)d_in[0];
    const float* w = (const float*)d_in[1];
    const float* gamma = (const float*)d_in[2];
    const float* beta = (const float*)d_in[3];
    float* out = (float*)d_out;

    float* wsf = (float*)d_ws;
    float* psum = wsf;                                   // 32*2048 f32
    float* psq = wsf + 32 * IN_DIM;                      // 32*2048 f32
    float* scale = wsf + 64 * IN_DIM;                    // 2048 f32
    float* shift = wsf + 65 * IN_DIM;                    // 2048 f32
    unsigned short* Bsgn = (unsigned short*)(wsf + 66 * IN_DIM);  // 8 MB
    unsigned short* Acat = Bsgn + (size_t)OUT_DIM * IN_DIM;       // 64 MB

    k_stats<<<dim3(8, 32), 256, 0, stream>>>(x, psum, psq);
    k_finalize<<<8, 256, 0, stream>>>(psum, psq, gamma, beta, scale, shift);
    k_prep_a<<<B_DIM, 256, 0, stream>>>(x, scale, shift, Acat);
    k_prep_b<<<OUT_DIM, 256, 0, stream>>>(w, Bsgn);
    k_gemm<<<NWG, 512, 0, stream>>>(Acat, Bsgn, out);
}

// Round 7
// 255.016 us; speedup vs baseline: 1.2550x; 1.2550x over previous
//
#include <hip/hip_runtime.h>
#include <hip/hip_bf16.h>

#define B_DIM 8192
#define IN_DIM 2048
#define OUT_DIM 2048
#define K2 (2 * IN_DIM)  // hi|lo concatenated K = 4096

typedef __attribute__((ext_vector_type(8))) __bf16 bf16x8;
typedef __attribute__((ext_vector_type(4))) float f32x4;

__device__ __forceinline__ unsigned short f32_to_bf16_rne(float f) {
    unsigned u = __float_as_uint(f);
    unsigned r = (u + 0x7FFFu + ((u >> 16) & 1u)) >> 16;
    return (unsigned short)r;
}
__device__ __forceinline__ float bf16u_to_f32(unsigned short h) {
    return __uint_as_float(((unsigned)h) << 16);
}

__device__ __forceinline__ void gload16(const void* g, void* l) {
    __builtin_amdgcn_global_load_lds(
        (const __attribute__((address_space(1))) void*)g,
        (__attribute__((address_space(3))) void*)l,
        16, 0, 0);
}

// ---------------- Stage 1: per-column partial sums (deterministic) -------------
__global__ void k_stats(const float* __restrict__ x, float* __restrict__ psum,
                        float* __restrict__ psq) {
    int col = blockIdx.x * 256 + threadIdx.x;
    int chunk = blockIdx.y;
    const float* p = x + (size_t)chunk * 256 * IN_DIM + col;
    float s = 0.f, s2 = 0.f;
#pragma unroll 8
    for (int r = 0; r < 256; ++r) {
        float v = p[(size_t)r * IN_DIM];
        s += v;
        s2 = fmaf(v, v, s2);
    }
    psum[chunk * IN_DIM + col] = s;
    psq[chunk * IN_DIM + col] = s2;
}

// ---------------- Stage 2: finalize mean/var -> scale/shift --------------------
__global__ void k_finalize(const float* __restrict__ psum, const float* __restrict__ psq,
                           const float* __restrict__ gamma, const float* __restrict__ beta,
                           float* __restrict__ scale, float* __restrict__ shift) {
    int c = blockIdx.x * 256 + threadIdx.x;
    float s = 0.f, s2 = 0.f;
#pragma unroll
    for (int ch = 0; ch < 32; ++ch) {
        s += psum[ch * IN_DIM + c];
        s2 += psq[ch * IN_DIM + c];
    }
    float mean = s * (1.0f / B_DIM);
    float var = fmaf(-mean, mean, s2 * (1.0f / B_DIM));
    float sc = gamma[c] * rsqrtf(var + 1e-5f);
    scale[c] = sc;
    shift[c] = fmaf(-mean, sc, beta[c]);
}

// ---------------- Stage 3: xn -> bf16 hi|lo, FRAGMENT-CONTIGUOUS layout --------
// A_perm: fragment block (r16 = row/16, k32 = k/32) stored as 512 elems:
// elem = ((r16*128 + k32)*64 + pos)*8 + j, pos = ((k>>3)&3)*16 + (row&15).
// pos == lane id of the MFMA A-fragment -> GEMM reads 64 lanes x 16B contiguous.
__global__ void k_prep_a(const float* __restrict__ x, const float* __restrict__ scale,
                         const float* __restrict__ shift, unsigned short* __restrict__ Ap) {
    int blk = blockIdx.x;          // 16-row stripe, 512 blocks
    int tid = threadIdx.x;
    int rowin = tid & 15;
    int cg = tid >> 4;             // 0..15
    int row = blk * 16 + rowin;
    const float* xr = x + (size_t)row * IN_DIM;
#pragma unroll
    for (int it = 0; it < 16; ++it) {
        int cgg = it * 16 + cg;    // 0..255 col-groups of 8
        int c0 = cgg * 8;
        float4 v0 = *(const float4*)(xr + c0);
        float4 v1 = *(const float4*)(xr + c0 + 4);
        float4 s0 = *(const float4*)(scale + c0);
        float4 s1 = *(const float4*)(scale + c0 + 4);
        float4 b0 = *(const float4*)(shift + c0);
        float4 b1 = *(const float4*)(shift + c0 + 4);
        float xs[8] = {v0.x, v0.y, v0.z, v0.w, v1.x, v1.y, v1.z, v1.w};
        float ss[8] = {s0.x, s0.y, s0.z, s0.w, s1.x, s1.y, s1.z, s1.w};
        float bb[8] = {b0.x, b0.y, b0.z, b0.w, b1.x, b1.y, b1.z, b1.w};
        union { unsigned short u[8]; uint4 v; } hi, lo;
#pragma unroll
        for (int j = 0; j < 8; ++j) {
            float xn = fmaf(xs[j], ss[j], bb[j]);
            unsigned short h = f32_to_bf16_rne(xn);
            float r = xn - bf16u_to_f32(h);
            hi.u[j] = h;
            lo.u[j] = f32_to_bf16_rne(r);
        }
        int k32 = cgg >> 2;
        int kgroup = cgg & 3;
        int pos = kgroup * 16 + rowin;
        size_t baseHi = ((size_t)blk * 128 + k32) * 512 + (size_t)pos * 8;
        size_t baseLo = ((size_t)blk * 128 + 64 + k32) * 512 + (size_t)pos * 8;
        *(uint4*)(Ap + baseHi) = hi.v;   // coalesced: consecutive tid -> consecutive 16B
        *(uint4*)(Ap + baseLo) = lo.v;
    }
}

// ---------------- Stage 4: weight sign -> bf16 +-1 [2048][2048] ----------------
__global__ void k_prep_b(const float* __restrict__ w, unsigned short* __restrict__ Bsgn) {
    int row = blockIdx.x;
    int c0 = threadIdx.x * 8;
    const float4* pw = (const float4*)(w + (size_t)row * IN_DIM + c0);
    float4 v0 = pw[0], v1 = pw[1];
    float wv[8] = {v0.x, v0.y, v0.z, v0.w, v1.x, v1.y, v1.z, v1.w};
    union { unsigned short u[8]; uint4 v; } sb;
#pragma unroll
    for (int j = 0; j < 8; ++j) sb.u[j] = (wv[j] >= 0.0f) ? 0x3F80u : 0xBF80u;
    *(uint4*)(Bsgn + (size_t)row * IN_DIM + c0) = sb.v;
}

// ---------------- Stage 5: 256x256 tile, A global->reg (coalesced), B LDS ring -
// A fragments: 8 x 1KB coalesced global_load_dwordx4 per wave per tile, double-
// buffered, issued one tile ahead. B: 4-deep LDS ring staged 2 tiles ahead.
// One barrier + one vmcnt(0) per K-tile; every load has >=3 phases of slack.
#define BM 256
#define BN 256
#define BK 64
#define MT (B_DIM / BM)    // 32
#define NT (OUT_DIM / BN)  // 8
#define NWG (MT * NT)      // 256
#define NKT (K2 / BK)      // 64
#define TILE_E (BN * BK)   // 16384 elems = 32 KB (one B buffer)

#define MEMF() asm volatile("" ::: "memory")
#define BARRIER() do { MEMF(); __builtin_amdgcn_s_barrier(); MEMF(); } while (0)
#define WAITVM(N) asm volatile("s_waitcnt vmcnt(" #N ")" ::: "memory")

__global__ __launch_bounds__(512, 2) void k_gemm(const unsigned short* __restrict__ A,
                                                 const unsigned short* __restrict__ Bsgn,
                                                 float* __restrict__ out) {
    __shared__ __align__(16) unsigned short sh[4 * TILE_E];  // 128 KiB B ring

    // T1: XCD-aware swizzle (256 % 8 == 0 -> bijective)
    int bid = blockIdx.x;
    int swz = (bid & 7) * (NWG / 8) + (bid >> 3);
    int mt = swz >> 3, nt = swz & 7;
    int m0 = mt * BM, n0 = nt * BN;

    int t = threadIdx.x;
    int lane = t & 63, w = t >> 6;
    int wm = w >> 1, wn = w & 1;         // 4m x 2n waves; per-wave out 64 x 128
    int lrow = lane & 15, lg = lane >> 4;
    int lq = lane >> 3, lslot = lane & 7;
    int tsl = lslot ^ lq;                // pre-swizzled source slot (row&7 == lq)

    int sl0 = (lg ^ (lane & 7)) << 3;          // ks=0 read slot offset (elems)
    int sl1 = ((lg + 4) ^ (lane & 7)) << 3;    // ks=1

    int bRd = (wn * 128 + lrow) * BK;

    // A_perm base for this wave: r16 = m0/16 + wm*4 (+m), frag-block stride 512
    const unsigned short* aBase =
        A + ((size_t)((m0 >> 4) + wm * 4) * 128) * 512 + (size_t)lane * 8;

    // B-chunk(2wn+i): pieces q = wm*2 + j (j=0..1); one gload16/thread per call
    auto stageB = [&](unsigned short* bbuf, int i, int j, int kt) {
        int cb = 2 * wn + i;
        int q = wm * 2 + j;
        const unsigned short* src =
            Bsgn + (size_t)(n0 + cb * 64 + q * 8 + lq) * IN_DIM +
            ((kt * BK) & (IN_DIM - 1)) + tsl * 8;
        gload16(src, bbuf + cb * (64 * BK) + q * 512 + lane * 8);
    };

    f32x4 acc[4][8] = {};

#define LDB(buf, n, sl) (*(const bf16x8*)&(buf)[bRd + (n) * (16 * BK) + (sl)])
#define LOADA(AF, KT)                                                              \
    do {                                                                           \
        _Pragma("unroll") for (int m_ = 0; m_ < 4; ++m_)                           \
            _Pragma("unroll") for (int ks_ = 0; ks_ < 2; ++ks_)                    \
                AF[m_][ks_] = *(const bf16x8*)(aBase + (size_t)m_ * 65536 +        \
                                               ((KT) * 2 + ks_) * 512);            \
    } while (0)
#define MFMA_PAIR(AF, NP, BP)                                                      \
    do {                                                                           \
        __builtin_amdgcn_s_setprio(1);                                             \
        _Pragma("unroll") for (int ks = 0; ks < 2; ++ks)                           \
            _Pragma("unroll") for (int m = 0; m < 4; ++m)                          \
                _Pragma("unroll") for (int i = 0; i < 2; ++i)                      \
                    acc[m][(NP) + i] = __builtin_amdgcn_mfma_f32_16x16x32_bf16(    \
                        AF[m][ks], BP[i][ks], acc[m][(NP) + i], 0, 0, 0);          \
        __builtin_amdgcn_s_setprio(0);                                             \
    } while (0)

    bf16x8 af0[4][2], af1[4][2];
    bf16x8 bpA[2][2], bpB[2][2], bpC[2][2], bpD[2][2];

    // Prologue: stage B(0)->buf0, B(1)->buf1; load af0 = A(0); drain; read bpA(0)
    {
        unsigned short* b0 = (unsigned short*)sh;
        unsigned short* b1 = (unsigned short*)sh + TILE_E;
        stageB(b0, 0, 0, 0); stageB(b0, 0, 1, 0); stageB(b0, 1, 0, 0); stageB(b0, 1, 1, 0);
        stageB(b1, 0, 0, 1); stageB(b1, 0, 1, 1); stageB(b1, 1, 0, 1); stageB(b1, 1, 1, 1);
        LOADA(af0, 0);
        WAITVM(0);
        BARRIER();
#pragma unroll
        for (int i = 0; i < 2; ++i) { bpA[i][0] = LDB((const unsigned short*)sh, i, sl0);
                                      bpA[i][1] = LDB((const unsigned short*)sh, i, sl1); }
    }

    auto tile_body = [&](int T_, bf16x8 (&AFC)[4][2], bf16x8 (&AFN)[4][2]) {
        const unsigned short* bufc = sh + (T_ & 3) * TILE_E;
        const unsigned short* bufn = sh + ((T_ + 1) & 3) * TILE_E;
        unsigned short* bufs = (unsigned short*)sh + ((T_ + 2) & 3) * TILE_E;
        bool st = T_ < NKT - 2, pf = T_ < NKT - 1;

        // ph0: issue next-next B staging + next-tile A loads; MFMA n{0,1}
        if (st) { stageB(bufs, 0, 0, T_ + 2); stageB(bufs, 0, 1, T_ + 2);
                  stageB(bufs, 1, 0, T_ + 2); stageB(bufs, 1, 1, T_ + 2); }
        if (pf) { LOADA(AFN, T_ + 1); }
#pragma unroll
        for (int i = 0; i < 2; ++i) { bpB[i][0] = LDB(bufc, 2 + i, sl0); bpB[i][1] = LDB(bufc, 2 + i, sl1); }
        MFMA_PAIR(AFC, 0, bpA);

        // ph1: MFMA n{2,3}
#pragma unroll
        for (int i = 0; i < 2; ++i) { bpC[i][0] = LDB(bufc, 4 + i, sl0); bpC[i][1] = LDB(bufc, 4 + i, sl1); }
        MFMA_PAIR(AFC, 2, bpB);

        // ph2: MFMA n{4,5}
#pragma unroll
        for (int i = 0; i < 2; ++i) { bpD[i][0] = LDB(bufc, 6 + i, sl0); bpD[i][1] = LDB(bufc, 6 + i, sl1); }
        MFMA_PAIR(AFC, 4, bpC);

        // ph3: drain (all loads 3 phases old), barrier; read next bpA; MFMA n{6,7}
        WAITVM(0);
        BARRIER();
        if (pf) {
#pragma unroll
            for (int i = 0; i < 2; ++i) { bpA[i][0] = LDB(bufn, i, sl0); bpA[i][1] = LDB(bufn, i, sl1); }
        }
        MFMA_PAIR(AFC, 6, bpD);
    };

    for (int T = 0; T < NKT; T += 2) {
        tile_body(T, af0, af1);
        tile_body(T + 1, af1, af0);
    }

    // Epilogue: C/D map col=lane&15, row=(lane>>4)*4+reg; fused hardtanh
#pragma unroll
    for (int m = 0; m < 4; ++m) {
#pragma unroll
        for (int n = 0; n < 8; ++n) {
#pragma unroll
            for (int r = 0; r < 4; ++r) {
                int row = m0 + wm * 64 + m * 16 + lg * 4 + r;
                int col = n0 + wn * 128 + n * 16 + lrow;
                float v = acc[m][n][r];
                v = fminf(fmaxf(v, -1.0f), 1.0f);
                out[(size_t)row * OUT_DIM + col] = v;
            }
        }
    }
}

extern "C" void kernel_launch(void* const* d_in, const int* in_sizes, int n_in,
                              void* d_out, int out_size, void* d_ws, size_t ws_size,
                              hipStream_t stream) {
    const float* x = (const float*)d_in[0];
    const float* w = (const float*)d_in[1];
    const float* gamma = (const float*)d_in[2];
    const float* beta = (const float*)d_in[3];
    float* out = (float*)d_out;

    float* wsf = (float*)d_ws;
    float* psum = wsf;                                   // 32*2048 f32
    float* psq = wsf + 32 * IN_DIM;                      // 32*2048 f32
    float* scale = wsf + 64 * IN_DIM;                    // 2048 f32
    float* shift = wsf + 65 * IN_DIM;                    // 2048 f32
    unsigned short* Bsgn = (unsigned short*)(wsf + 66 * IN_DIM);  // 8 MB
    unsigned short* Aperm = Bsgn + (size_t)OUT_DIM * IN_DIM;      // 64 MB

    k_stats<<<dim3(8, 32), 256, 0, stream>>>(x, psum, psq);
    k_finalize<<<8, 256, 0, stream>>>(psum, psq, gamma, beta, scale, shift);
    k_prep_a<<<512, 256, 0, stream>>>(x, scale, shift, Aperm);
    k_prep_b<<<OUT_DIM, 256, 0, stream>>>(w, Bsgn);
    k_gemm<<<NWG, 512, 0, stream>>>(Aperm, Bsgn, out);
}

// Round 8
// 232.504 us; speedup vs baseline: 1.3765x; 1.0968x over previous
//
#include <hip/hip_runtime.h>
#include <hip/hip_bf16.h>

#define B_DIM 8192
#define IN_DIM 2048
#define OUT_DIM 2048
#define K2 (2 * IN_DIM)  // hi|lo concatenated K = 4096

typedef __attribute__((ext_vector_type(8))) __bf16 bf16x8;
typedef __attribute__((ext_vector_type(4))) float f32x4;

__device__ __forceinline__ unsigned short f32_to_bf16_rne(float f) {
    unsigned u = __float_as_uint(f);
    unsigned r = (u + 0x7FFFu + ((u >> 16) & 1u)) >> 16;
    return (unsigned short)r;
}
__device__ __forceinline__ float bf16u_to_f32(unsigned short h) {
    return __uint_as_float(((unsigned)h) << 16);
}

__device__ __forceinline__ void gload16(const void* g, void* l) {
    __builtin_amdgcn_global_load_lds(
        (const __attribute__((address_space(1))) void*)g,
        (__attribute__((address_space(3))) void*)l,
        16, 0, 0);
}

// ---------------- Stage 1: per-column partial sums (deterministic) -------------
__global__ void k_stats(const float* __restrict__ x, float* __restrict__ psum,
                        float* __restrict__ psq) {
    int col = blockIdx.x * 256 + threadIdx.x;
    int chunk = blockIdx.y;
    const float* p = x + (size_t)chunk * 256 * IN_DIM + col;
    float s = 0.f, s2 = 0.f;
#pragma unroll 8
    for (int r = 0; r < 256; ++r) {
        float v = p[(size_t)r * IN_DIM];
        s += v;
        s2 = fmaf(v, v, s2);
    }
    psum[chunk * IN_DIM + col] = s;
    psq[chunk * IN_DIM + col] = s2;
}

// ---------------- Stage 2: finalize mean/var -> scale/shift --------------------
__global__ void k_finalize(const float* __restrict__ psum, const float* __restrict__ psq,
                           const float* __restrict__ gamma, const float* __restrict__ beta,
                           float* __restrict__ scale, float* __restrict__ shift) {
    int c = blockIdx.x * 256 + threadIdx.x;
    float s = 0.f, s2 = 0.f;
#pragma unroll
    for (int ch = 0; ch < 32; ++ch) {
        s += psum[ch * IN_DIM + c];
        s2 += psq[ch * IN_DIM + c];
    }
    float mean = s * (1.0f / B_DIM);
    float var = fmaf(-mean, mean, s2 * (1.0f / B_DIM));
    float sc = gamma[c] * rsqrtf(var + 1e-5f);
    scale[c] = sc;
    shift[c] = fmaf(-mean, sc, beta[c]);
}

// ---------------- Stage 3: xn -> bf16 hi|lo concatenated A [8192][4096] --------
__global__ void k_prep_a(const float* __restrict__ x, const float* __restrict__ scale,
                         const float* __restrict__ shift, unsigned short* __restrict__ Acat) {
    int row = blockIdx.x;
    int c0 = threadIdx.x * 8;
    const float4* px = (const float4*)(x + (size_t)row * IN_DIM + c0);
    float4 v0 = px[0], v1 = px[1];
    const float4* ps = (const float4*)(scale + c0);
    float4 s0 = ps[0], s1 = ps[1];
    const float4* pb = (const float4*)(shift + c0);
    float4 b0 = pb[0], b1 = pb[1];
    float xs[8] = {v0.x, v0.y, v0.z, v0.w, v1.x, v1.y, v1.z, v1.w};
    float ss[8] = {s0.x, s0.y, s0.z, s0.w, s1.x, s1.y, s1.z, s1.w};
    float bb[8] = {b0.x, b0.y, b0.z, b0.w, b1.x, b1.y, b1.z, b1.w};
    union { unsigned short u[8]; uint4 v; } hi, lo;
#pragma unroll
    for (int j = 0; j < 8; ++j) {
        float xn = fmaf(xs[j], ss[j], bb[j]);
        unsigned short h = f32_to_bf16_rne(xn);
        float r = xn - bf16u_to_f32(h);
        hi.u[j] = h;
        lo.u[j] = f32_to_bf16_rne(r);
    }
    size_t base = (size_t)row * K2;
    *(uint4*)(Acat + base + c0) = hi.v;
    *(uint4*)(Acat + base + IN_DIM + c0) = lo.v;
}

// ---------------- Stage 4: weight sign -> bf16 +-1 [2048][2048] ----------------
__global__ void k_prep_b(const float* __restrict__ w, unsigned short* __restrict__ Bsgn) {
    int row = blockIdx.x;
    int c0 = threadIdx.x * 8;
    const float4* pw = (const float4*)(w + (size_t)row * IN_DIM + c0);
    float4 v0 = pw[0], v1 = pw[1];
    float wv[8] = {v0.x, v0.y, v0.z, v0.w, v1.x, v1.y, v1.z, v1.w};
    union { unsigned short u[8]; uint4 v; } sb;
#pragma unroll
    for (int j = 0; j < 8; ++j) sb.u[j] = (wv[j] >= 0.0f) ? 0x3F80u : 0xBF80u;
    *(uint4*)(Bsgn + (size_t)row * IN_DIM + c0) = sb.v;
}

// ---------------- Stage 5: 256x256 double-K tile GEMM (B staged ONCE) ----------
// K-loop over original 2048 (32 tiles). Per tile: stage B once (32KB, dbuf) +
// A-hi/A-lo (64KB, single-buffered -- each wave holds its full A in regs after
// the tile-start read, so Abuf is dead from ph1 on). B fragments are read into
// registers once and used against BOTH A halves -> LDS traffic/work drops from
// 512KB to 352KB per double-tile, below the 4966cy MFMA floor.
#define BM 256
#define BN 256
#define BK 64
#define NWG ((B_DIM / BM) * (OUT_DIM / BN))  // 256
#define NKT (IN_DIM / BK)                    // 32 double-tiles
// LDS map (elements): A-hi 0, A-lo 16384, B0 32768, B1 49152  (128 KiB total)

#define MEMF() asm volatile("" ::: "memory")
#define BARRIER() do { MEMF(); __builtin_amdgcn_s_barrier(); MEMF(); } while (0)
#define WAITVM(N) asm volatile("s_waitcnt vmcnt(" #N ")" ::: "memory")
#define WAITLGKM0() asm volatile("s_waitcnt lgkmcnt(0)" ::: "memory")

__global__ __launch_bounds__(512, 2) void k_gemm(const unsigned short* __restrict__ A,
                                                 const unsigned short* __restrict__ Bsgn,
                                                 float* __restrict__ out) {
    __shared__ __align__(16) unsigned short sh[65536];  // 128 KiB

    // T1: XCD-aware swizzle (256 % 8 == 0 -> bijective)
    int bid = blockIdx.x;
    int swz = (bid & 7) * (NWG / 8) + (bid >> 3);
    int mt = swz >> 3, nt = swz & 7;
    int m0 = mt * BM, n0 = nt * BN;

    int t = threadIdx.x;
    int lane = t & 63, w = t >> 6;
    int wm = w >> 1, wn = w & 1;         // 4m x 2n waves; per-wave out 64 x 128
    int lrow = lane & 15, lg = lane >> 4;
    int lq = lane >> 3, lslot = lane & 7;
    int tsl = lslot ^ lq;                // pre-swizzled source slot (row&7 == lq)

    int sl0 = (lg ^ (lane & 7)) << 3;          // ks=0 read slot offset (elems)
    int sl1 = ((lg + 4) ^ (lane & 7)) << 3;    // ks=1

    int aRd = (wm * 64 + lrow) * BK;
    int bRd = (wn * 128 + lrow) * BK;

    // A staging: wave stages its own 64 rows, half h, piece j (4 per half)
    auto stageA = [&](int h, int j, int kt) {
        int q = wn * 4 + j;
        const unsigned short* src =
            A + (size_t)(m0 + wm * 64 + q * 8 + lq) * K2 + h * IN_DIM + kt * BK + tsl * 8;
        gload16(src, (unsigned short*)sh + h * 16384 + wm * 4096 + q * 512 + lane * 8);
    };
    // B staging into buffer bbuf: chunk cb=2wn+i, piece q=wm*2+j
    auto stageB = [&](unsigned short* bbuf, int i, int j, int kt) {
        int cb = 2 * wn + i;
        int q = wm * 2 + j;
        const unsigned short* src =
            Bsgn + (size_t)(n0 + cb * 64 + q * 8 + lq) * IN_DIM + kt * BK + tsl * 8;
        gload16(src, bbuf + cb * 4096 + q * 512 + lane * 8);
    };

    f32x4 acc[4][8] = {};

#define LDAF(h, m, sl) (*(const bf16x8*)&sh[(h) * 16384 + aRd + (m) * 1024 + (sl)])
#define LDB(buf, n, sl) (*(const bf16x8*)&(buf)[bRd + (n) * 1024 + (sl)])
// 32 MFMAs: both K-slices x both A-halves x 4m x 2n; deps 8 apart
#define MFMA32(NP, BP)                                                             \
    do {                                                                           \
        __builtin_amdgcn_s_setprio(1);                                             \
        _Pragma("unroll") for (int ks = 0; ks < 2; ++ks)                           \
            _Pragma("unroll") for (int h = 0; h < 2; ++h)                          \
                _Pragma("unroll") for (int m = 0; m < 4; ++m)                      \
                    _Pragma("unroll") for (int i = 0; i < 2; ++i)                  \
                        acc[m][(NP) + i] = __builtin_amdgcn_mfma_f32_16x16x32_bf16(\
                            af[m][ks][h], BP[i][ks], acc[m][(NP) + i], 0, 0, 0);   \
        __builtin_amdgcn_s_setprio(0);                                             \
    } while (0)

    bf16x8 af[4][2][2];   // [m][ks][half] -- full tile's A for this wave
    bf16x8 bpA[2][2], bpB[2][2], bpC[2][2], bpD[2][2];

    // Prologue: B(0)->B0, A(0) hi+lo, B(1)->B1 (stays in flight); read af, bpA.
    {
        unsigned short* B0 = (unsigned short*)sh + 32768;
        unsigned short* B1 = (unsigned short*)sh + 49152;
        stageB(B0, 0, 0, 0); stageB(B0, 0, 1, 0); stageB(B0, 1, 0, 0); stageB(B0, 1, 1, 0);
        stageA(0, 0, 0); stageA(0, 1, 0); stageA(0, 2, 0); stageA(0, 3, 0);
        stageA(1, 0, 0); stageA(1, 1, 0); stageA(1, 2, 0); stageA(1, 3, 0);
        stageB(B1, 0, 0, 1); stageB(B1, 0, 1, 1); stageB(B1, 1, 0, 1); stageB(B1, 1, 1, 1);
        WAITVM(4);
        BARRIER();
#pragma unroll
        for (int m = 0; m < 4; ++m)
#pragma unroll
            for (int h = 0; h < 2; ++h) { af[m][0][h] = LDAF(h, m, sl0); af[m][1][h] = LDAF(h, m, sl1); }
#pragma unroll
        for (int i = 0; i < 2; ++i) { bpA[i][0] = LDB(B0, i, sl0); bpA[i][1] = LDB(B0, i, sl1); }
    }

#pragma unroll 2
    for (int T = 0; T < NKT; ++T) {
        const unsigned short* Bcur = sh + 32768 + (T & 1) * 16384;
        unsigned short* Bnxt = (unsigned short*)sh + 32768 + ((T + 1) & 1) * 16384;
        bool pf = (T < NKT - 1);
        int kn = T + 1;

        // ph0: read bpB; stage B(T+1); MFMA n{0,1}; barrier (A-reads all done)
#pragma unroll
        for (int i = 0; i < 2; ++i) { bpB[i][0] = LDB(Bcur, 2 + i, sl0); bpB[i][1] = LDB(Bcur, 2 + i, sl1); }
        if (pf) { stageB(Bnxt, 0, 0, kn); stageB(Bnxt, 0, 1, kn);
                  stageB(Bnxt, 1, 0, kn); stageB(Bnxt, 1, 1, kn); }
        MFMA32(0, bpA);
        WAITLGKM0();
        BARRIER();

        // ph1: read bpC; stage A(T+1) hi+lo into Abuf (now dead); MFMA n{2,3}
#pragma unroll
        for (int i = 0; i < 2; ++i) { bpC[i][0] = LDB(Bcur, 4 + i, sl0); bpC[i][1] = LDB(Bcur, 4 + i, sl1); }
        if (pf) { stageA(0, 0, kn); stageA(0, 1, kn); stageA(0, 2, kn); stageA(0, 3, kn);
                  stageA(1, 0, kn); stageA(1, 1, kn); stageA(1, 2, kn); stageA(1, 3, kn); }
        MFMA32(2, bpB);

        // ph2: read bpD; MFMA n{4,5}; drain all staging; barrier (publish)
#pragma unroll
        for (int i = 0; i < 2; ++i) { bpD[i][0] = LDB(Bcur, 6 + i, sl0); bpD[i][1] = LDB(Bcur, 6 + i, sl1); }
        MFMA32(4, bpC);
        WAITVM(0);
        WAITLGKM0();
        BARRIER();

        // ph3: MFMA n{6,7}; then read next tile's af (Abuf) + bpA (Bnxt)
        MFMA32(6, bpD);
        if (pf) {
#pragma unroll
            for (int m = 0; m < 4; ++m)
#pragma unroll
                for (int h = 0; h < 2; ++h) { af[m][0][h] = LDAF(h, m, sl0); af[m][1][h] = LDAF(h, m, sl1); }
#pragma unroll
            for (int i = 0; i < 2; ++i) { bpA[i][0] = LDB(Bnxt, i, sl0); bpA[i][1] = LDB(Bnxt, i, sl1); }
        }
    }

    // Epilogue: C/D map col=lane&15, row=(lane>>4)*4+reg; fused hardtanh
#pragma unroll
    for (int m = 0; m < 4; ++m) {
#pragma unroll
        for (int n = 0; n < 8; ++n) {
#pragma unroll
            for (int r = 0; r < 4; ++r) {
                int row = m0 + wm * 64 + m * 16 + lg * 4 + r;
                int col = n0 + wn * 128 + n * 16 + lrow;
                float v = acc[m][n][r];
                v = fminf(fmaxf(v, -1.0f), 1.0f);
                out[(size_t)row * OUT_DIM + col] = v;
            }
        }
    }
}

extern "C" void kernel_launch(void* const* d_in, const int* in_sizes, int n_in,
                              void* d_out, int out_size, void* d_ws, size_t ws_size,
                              hipStream_t stream) {
    const float* x = (const float*)d_in[0];
    const float* w = (const float*)d_in[1];
    const float* gamma = (const float*)d_in[2];
    const float* beta = (const float*)d_in[3];
    float* out = (float*)d_out;

    float* wsf = (float*)d_ws;
    float* psum = wsf;                                   // 32*2048 f32
    float* psq = wsf + 32 * IN_DIM;                      // 32*2048 f32
    float* scale = wsf + 64 * IN_DIM;                    // 2048 f32
    float* shift = wsf + 65 * IN_DIM;                    // 2048 f32
    unsigned short* Bsgn = (unsigned short*)(wsf + 66 * IN_DIM);  // 8 MB
    unsigned short* Acat = Bsgn + (size_t)OUT_DIM * IN_DIM;       // 64 MB

    k_stats<<<dim3(8, 32), 256, 0, stream>>>(x, psum, psq);
    k_finalize<<<8, 256, 0, stream>>>(psum, psq, gamma, beta, scale, shift);
    k_prep_a<<<B_DIM, 256, 0, stream>>>(x, scale, shift, Acat);
    k_prep_b<<<OUT_DIM, 256, 0, stream>>>(w, Bsgn);
    k_gemm<<<NWG, 512, 0, stream>>>(Acat, Bsgn, out);
}